// Round 3
// baseline (14809.245 us; speedup 1.0000x reference)
//
#include <hip/hip_runtime.h>
#include <stdint.h>

typedef unsigned int uint32;
typedef unsigned short u16;
typedef unsigned long long u64;
typedef __attribute__((ext_vector_type(8))) short short8;   // 8 bf16 (4 VGPR) MFMA A/B frag
typedef __attribute__((ext_vector_type(4))) float f32x4;    // MFMA C/D frag

#define HASH_BITS 19
#define TABLE_SZ (1u << HASH_BITS)
#define HMASK (TABLE_SZ - 1u)
#define PI_D 3.141592653589793
#define NPTS 131072

__device__ __forceinline__ u16 f2bf(float f) {  // RNE f32->bf16
    uint32 u = __float_as_uint(f);
    u += 0x7FFFu + ((u >> 16) & 1u);
    return (u16)(u >> 16);
}
__device__ __forceinline__ float bf2f(uint32 u) { return __uint_as_float(u << 16); }

// floor(16 * 2^(l/3)) exactly as the f32 reference computes it
__device__ const float g_res[16] = {16.f,20.f,25.f,32.f,40.f,50.f,64.f,80.f,
                                    101.f,128.f,161.f,203.f,256.f,322.f,406.f,512.f};

// Convert W2..W5 (512x512) and W6 (512x16) to bf16, transposed to [n][k].
__global__ void prep_weights(const float* __restrict__ W2, const float* __restrict__ W3,
                             const float* __restrict__ W4, const float* __restrict__ W5,
                             const float* __restrict__ W6, u16* __restrict__ wt) {
    int tid = blockIdx.x * 256 + threadIdx.x;
    const int NW = 4 * 512 * 512;
    if (tid < NW) {
        int m = tid >> 18;
        int rem = tid & 262143;
        int n = rem >> 9, k = rem & 511;
        const float* W = (m == 0) ? W2 : (m == 1) ? W3 : (m == 2) ? W4 : W5;
        wt[tid] = f2bf(W[k * 512 + n]);
    } else if (tid < NW + 16 * 512) {
        int rem = tid - NW;
        int j = rem >> 9, k = rem & 511;
        wt[tid] = f2bf(W6[k * 16 + j]);
    }
}

__global__ void mask_kernel(const float* __restrict__ x, float* __restrict__ mout, int B) {
    int i = blockIdx.x * 256 + threadIdx.x;
    if (i >= B) return;
    constexpr float bmin[4] = {0.0f, (float)(-PI_D), (float)(0.5 * PI_D), (float)(-0.85 * PI_D)};
    constexpr float bmax[4] = {(float)(PI_D), (float)(PI_D), (float)(0.85 * PI_D), (float)(-0.5 * PI_D)};
    float4 v = ((const float4*)x)[i];
    bool ok = (v.x >= bmin[0]) && (v.x <= bmax[0]) &&
              (v.y >= bmin[1]) && (v.y <= bmax[1]) &&
              (v.z >= bmin[2]) && (v.z <= bmax[2]) &&
              (v.w >= bmin[3]) && (v.w <= bmax[3]);
    mout[i] = ok ? 1.0f : 0.0f;
}

// Phase A: one block = 128 points x 1 level, 16 waves. Computes the weight-MLP
// softmax weights. two_phase=1: store w (bf16) to wq and exit (gathers live in
// a separate kernel so table traffic never pollutes the weight-holding L2).
// two_phase=0 fallback: inline gather (if ws_size too small for wq).
__global__ __launch_bounds__(1024, 4)
void fused_mlp(const float* __restrict__ x, const float* __restrict__ tables,
               const float* __restrict__ W1, const float* __restrict__ b1,
               const u16* __restrict__ wt,
               const float* __restrict__ b2, const float* __restrict__ b3,
               const float* __restrict__ b4, const float* __restrict__ b5,
               const float* __restrict__ b6, u16* __restrict__ wq,
               float* __restrict__ out, int two_phase) {
    __shared__ u16 act[128 * 512];         // 128KB activations (XOR-swizzled)
    __shared__ float xsh[128 * 4];
    __shared__ float zsh[128 * 17];        // logits
    __shared__ float wsh[128 * 17];        // softmax weights (fallback path only)

    const int tid = threadIdx.x;
    const int lane = tid & 63;
    const int wv = tid >> 6;               // wave 0..15
    const int ptile = blockIdx.x;          // 1024 tiles of 128 points
    const int level = blockIdx.y;
    const float res = g_res[level];

    if (tid < 512) xsh[tid] = x[ptile * 512 + tid];
    __syncthreads();

    // ---- layer 1: feat=[res,x] (K=5) -> 512, VALU. thread: col n=tid&511, half tid>>9.
    {
        const int n = tid & 511;
        const int ph = tid >> 9;
        float w0 = W1[n], w1 = W1[512 + n], w2 = W1[1024 + n],
              w3 = W1[1536 + n], w4 = W1[2048 + n];
        float base = fmaf(res, w0, b1[n]);
        const int u0 = n >> 3, nlo = n & 7;
        for (int pp = 0; pp < 64; ++pp) {
            int p = ph * 64 + pp;
            float v = base;
            v = fmaf(xsh[p * 4 + 0], w1, v);
            v = fmaf(xsh[p * 4 + 1], w2, v);
            v = fmaf(xsh[p * 4 + 2], w3, v);
            v = fmaf(xsh[p * 4 + 3], w4, v);
            v = fmaxf(v, 0.0f);
            act[p * 512 + ((u0 ^ (p & 7)) << 3) + nlo] = f2bf(v);
        }
    }
    __syncthreads();

    // ---- layers 2..5: 512x512 bf16 MFMA. wave grid 2x8: 64 rows x 64 cols each.
    const int row = lane & 15;
    const int kg = lane >> 4;
    const int wr = wv >> 3;                // row half 0..1
    const int wc = wv & 7;                 // col group 0..7
    for (int ly = 0; ly < 4; ++ly) {
        const u16* wbase = wt + ly * 262144;
        const float* bias = (ly == 0) ? b2 : (ly == 1) ? b3 : (ly == 2) ? b4 : b5;
        f32x4 acc[4][4];
#pragma unroll
        for (int rt = 0; rt < 4; ++rt)
#pragma unroll
            for (int ct = 0; ct < 4; ++ct) acc[rt][ct] = (f32x4){0.f, 0.f, 0.f, 0.f};

#pragma unroll 4
        for (int kk = 0; kk < 16; ++kk) {
            const int k0 = kk * 32 + kg * 8;
            short8 a[4], b[4];
#pragma unroll
            for (int rt = 0; rt < 4; ++rt) {
                int r = wr * 64 + rt * 16 + row;
                int u = (k0 >> 3) ^ (r & 7);
                a[rt] = *(const short8*)&act[r * 512 + (u << 3)];
            }
#pragma unroll
            for (int ct = 0; ct < 4; ++ct) {
                int col = wc * 64 + ct * 16 + row;
                b[ct] = *(const short8*)&wbase[col * 512 + k0];
            }
#pragma unroll
            for (int rt = 0; rt < 4; ++rt)
#pragma unroll
                for (int ct = 0; ct < 4; ++ct)
                    acc[rt][ct] = __builtin_amdgcn_mfma_f32_16x16x32_bf16(a[rt], b[ct], acc[rt][ct], 0, 0, 0);
        }
        __syncthreads();   // all waves done reading act
#pragma unroll
        for (int ct = 0; ct < 4; ++ct) {
            int col = wc * 64 + ct * 16 + row;
            float bv = bias[col];
            int ucol = col >> 3, clo = col & 7;
#pragma unroll
            for (int rt = 0; rt < 4; ++rt)
#pragma unroll
                for (int q = 0; q < 4; ++q) {
                    int rg = wr * 64 + rt * 16 + kg * 4 + q;
                    float v = fmaxf(acc[rt][ct][q] + bv, 0.0f);
                    act[rg * 512 + ((ucol ^ (rg & 7)) << 3) + clo] = f2bf(v);
                }
        }
        __syncthreads();
    }

    // ---- layer 6: 512 -> 16 logits via MFMA on waves 0..7 (16 rows each)
    if (wv < 8) {
        const u16* w6 = wt + 4 * 262144;
        f32x4 acc = {0.f, 0.f, 0.f, 0.f};
        const int r = wv * 16 + row;
#pragma unroll 4
        for (int kk = 0; kk < 16; ++kk) {
            int k0 = kk * 32 + kg * 8;
            int u = (k0 >> 3) ^ (r & 7);
            short8 a = *(const short8*)&act[r * 512 + (u << 3)];
            short8 b = *(const short8*)&w6[row * 512 + k0];
            acc = __builtin_amdgcn_mfma_f32_16x16x32_bf16(a, b, acc, 0, 0, 0);
        }
        float bv = b6[row];
#pragma unroll
        for (int q = 0; q < 4; ++q) {
            int rg = wv * 16 + kg * 4 + q;
            zsh[rg * 17 + row] = acc[q] + bv;
        }
    }
    __syncthreads();

    // ---- softmax over 16 (threads 0..127, one point each)
    if (tid < 128) {
        float zv[16];
        float m = -1e30f;
#pragma unroll
        for (int j = 0; j < 16; ++j) { zv[j] = zsh[tid * 17 + j]; m = fmaxf(m, zv[j]); }
        float s = 0.f;
#pragma unroll
        for (int j = 0; j < 16; ++j) { zv[j] = expf(zv[j] - m); s += zv[j]; }
        float inv = 1.0f / s;
        if (two_phase) {
            u16* wp = wq + ((size_t)level * NPTS + ptile * 128 + tid) * 16;
#pragma unroll
            for (int j = 0; j < 16; ++j) wp[j] = f2bf(zv[j] * inv);
        } else {
#pragma unroll
            for (int j = 0; j < 16; ++j) wsh[tid * 17 + j] = zv[j] * inv;
        }
    }

    if (two_phase) return;
    __syncthreads();

    // ---- fallback inline gather: 8 threads/point, 2 corners each.
    {
        constexpr float bmin[4] = {0.0f, (float)(-PI_D), (float)(0.5 * PI_D), (float)(-0.85 * PI_D)};
        constexpr float bmax[4] = {(float)(PI_D), (float)(PI_D), (float)(0.85 * PI_D), (float)(-0.5 * PI_D)};
        constexpr uint32 primes[4] = {1u, 2654435761u, 805459861u, 3674653429u};
        const int p = tid >> 3;
        const int pr = tid & 7;
        uint32 ca[4], cb[4];
#pragma unroll
        for (int d = 0; d < 4; ++d) {
            float xv = xsh[p * 4 + d];
            float xc = fminf(fmaxf(xv, bmin[d]), bmax[d]);
            float g = (bmax[d] - bmin[d]) / res;
            float t = (xc - bmin[d]) / g;
            int bl = (int)floorf(t);
            ca[d] = (uint32)bl * primes[d];
            cb[d] = (uint32)(bl + 1) * primes[d];
        }
        float s0 = 0.f, s1 = 0.f;
        const float* tb = tables + (size_t)level * TABLE_SZ * 2;
#pragma unroll
        for (int vv = 0; vv < 2; ++vv) {
            int v = pr * 2 + vv;
            uint32 h = ((v & 8) ? cb[0] : ca[0]) ^ ((v & 4) ? cb[1] : ca[1]) ^
                       ((v & 2) ? cb[2] : ca[2]) ^ ((v & 1) ? cb[3] : ca[3]);
            float2 e = *(const float2*)(tb + (size_t)(h & HMASK) * 2);
            float wgt = wsh[p * 17 + v];
            s0 = fmaf(wgt, e.x, s0);
            s1 = fmaf(wgt, e.y, s1);
        }
#pragma unroll
        for (int sft = 1; sft < 8; sft <<= 1) {
            s0 += __shfl_xor(s0, sft, 64);
            s1 += __shfl_xor(s1, sft, 64);
        }
        if (pr == 0) {
            float* o = out + (size_t)(ptile * 128 + p) * 32 + level * 2;
            o[0] = s0;
            o[1] = s1;
        }
    }
}

// Phase B: pure gather. Block = 256 points x 1 level; same-level blocks cluster
// in dispatch so each 4MB table is L2-resident with nothing competing.
__global__ __launch_bounds__(256, 8)
void gather_kernel(const float* __restrict__ x, const float* __restrict__ tables,
                   const u16* __restrict__ wq, float* __restrict__ out) {
    const int level = blockIdx.y;
    const int p = blockIdx.x * 256 + threadIdx.x;
    const float res = g_res[level];
    constexpr float bmin[4] = {0.0f, (float)(-PI_D), (float)(0.5 * PI_D), (float)(-0.85 * PI_D)};
    constexpr float bmax[4] = {(float)(PI_D), (float)(PI_D), (float)(0.85 * PI_D), (float)(-0.5 * PI_D)};
    constexpr uint32 primes[4] = {1u, 2654435761u, 805459861u, 3674653429u};

    float4 xv4 = ((const float4*)x)[p];
    float xd[4] = {xv4.x, xv4.y, xv4.z, xv4.w};
    uint32 ca[4], cb[4];
#pragma unroll
    for (int d = 0; d < 4; ++d) {
        float xc = fminf(fmaxf(xd[d], bmin[d]), bmax[d]);
        float g = (bmax[d] - bmin[d]) / res;
        float t = (xc - bmin[d]) / g;
        int bl = (int)floorf(t);
        ca[d] = (uint32)bl * primes[d];
        cb[d] = (uint32)(bl + 1) * primes[d];
    }
    // softmax weights: 16 bf16 = 32B contiguous
    const uint4* wp = (const uint4*)(wq + ((size_t)level * NPTS + p) * 16);
    uint4 wa = wp[0], wb = wp[1];
    uint32 wu[8] = {wa.x, wa.y, wa.z, wa.w, wb.x, wb.y, wb.z, wb.w};

    const float* tb = tables + (size_t)level * TABLE_SZ * 2;
    float s0 = 0.f, s1 = 0.f;
#pragma unroll
    for (int v = 0; v < 16; ++v) {
        uint32 h = ((v & 8) ? cb[0] : ca[0]) ^ ((v & 4) ? cb[1] : ca[1]) ^
                   ((v & 2) ? cb[2] : ca[2]) ^ ((v & 1) ? cb[3] : ca[3]);
        float2 e = *(const float2*)(tb + (size_t)(h & HMASK) * 2);
        float wgt = bf2f((v & 1) ? (wu[v >> 1] >> 16) : (wu[v >> 1] & 0xFFFFu));
        s0 = fmaf(wgt, e.x, s0);
        s1 = fmaf(wgt, e.y, s1);
    }
    float* o = out + (size_t)p * 32 + level * 2;
    __builtin_nontemporal_store(s0, o);
    __builtin_nontemporal_store(s1, o + 1);
}

extern "C" void kernel_launch(void* const* d_in, const int* in_sizes, int n_in,
                              void* d_out, int out_size, void* d_ws, size_t ws_size,
                              hipStream_t stream) {
    const float* x      = (const float*)d_in[0];
    const float* tables = (const float*)d_in[1];
    const float* W1 = (const float*)d_in[2];
    const float* b1 = (const float*)d_in[3];
    const float* W2 = (const float*)d_in[4];
    const float* b2 = (const float*)d_in[5];
    const float* W3 = (const float*)d_in[6];
    const float* b3 = (const float*)d_in[7];
    const float* W4 = (const float*)d_in[8];
    const float* b4 = (const float*)d_in[9];
    const float* W5 = (const float*)d_in[10];
    const float* b5 = (const float*)d_in[11];
    const float* W6 = (const float*)d_in[12];
    const float* b6 = (const float*)d_in[13];

    const int B = in_sizes[0] / 4;          // 131072
    u16* wt = (u16*)d_ws;                   // 2.02 MB weights (bf16, transposed)
    u16* wq = (u16*)((char*)d_ws + (4 << 20));  // 64 MB softmax weights
    const size_t need = (size_t)(4 << 20) + (size_t)16 * NPTS * 16 * 2;
    const int two_phase = (ws_size >= need) ? 1 : 0;

    const int prep_elems = 4 * 512 * 512 + 16 * 512;
    prep_weights<<<(prep_elems + 255) / 256, 256, 0, stream>>>(W2, W3, W4, W5, W6, wt);

    dim3 gridA(B / 128, 16);
    fused_mlp<<<gridA, 1024, 0, stream>>>(x, tables, W1, b1, wt, b2, b3, b4, b5, b6,
                                          wq, (float*)d_out, two_phase);
    if (two_phase) {
        dim3 gridB(B / 256, 16);
        gather_kernel<<<gridB, 256, 0, stream>>>(x, tables, wq, (float*)d_out);
    }
    mask_kernel<<<(B + 255) / 256, 256, 0, stream>>>(x, (float*)d_out + (size_t)B * 32, B);
}

// Round 4
// 6902.851 us; speedup vs baseline: 2.1454x; 2.1454x over previous
//
#include <hip/hip_runtime.h>
#include <stdint.h>

typedef unsigned int uint32;
typedef unsigned short u16;
typedef unsigned long long u64;
typedef __attribute__((ext_vector_type(8))) short short8;   // 8 bf16 (4 VGPR) MFMA A/B frag
typedef __attribute__((ext_vector_type(4))) float f32x4;    // MFMA C/D frag

#define HASH_BITS 19
#define TABLE_SZ (1u << HASH_BITS)
#define HMASK (TABLE_SZ - 1u)
#define PI_D 3.141592653589793
#define NPTS 131072

__device__ __forceinline__ u16 f2bf(float f) {  // RNE f32->bf16
    uint32 u = __float_as_uint(f);
    u += 0x7FFFu + ((u >> 16) & 1u);
    return (u16)(u >> 16);
}
__device__ __forceinline__ float bf2f(uint32 u) { return __uint_as_float(u << 16); }

// floor(16 * 2^(l/3)) exactly as the f32 reference computes it
__device__ const float g_res[16] = {16.f,20.f,25.f,32.f,40.f,50.f,64.f,80.f,
                                    101.f,128.f,161.f,203.f,256.f,322.f,406.f,512.f};

// W2..W5 (512x512) and W6 (512x16) -> bf16, tiled so one wave B-frag load for
// (colgroup g, kstep kk) is ONE contiguous 1KB block:
//   block[lane*8 + j] = W[col = g*16 + (lane&15)][k = kk*32 + (lane>>4)*8 + j]
__global__ void prep_weights(const float* __restrict__ W2, const float* __restrict__ W3,
                             const float* __restrict__ W4, const float* __restrict__ W5,
                             const float* __restrict__ W6, u16* __restrict__ wt) {
    int tid = blockIdx.x * 256 + threadIdx.x;
    const int NW = 4 * 512 * 512;
    if (tid < NW) {
        int m = tid >> 18;
        int rem = tid & 262143;
        int n = rem >> 9, k = rem & 511;          // n = output col, k = input
        const float* W = (m == 0) ? W2 : (m == 1) ? W3 : (m == 2) ? W4 : W5;
        int g = n >> 4, r = n & 15, kk = k >> 5, kg = (k >> 3) & 3, j = k & 7;
        int dst = m * 262144 + g * 8192 + kk * 512 + (kg * 16 + r) * 8 + j;
        wt[dst] = f2bf(W[k * 512 + n]);
    } else if (tid < NW + 16 * 512) {
        int rem = tid - NW;
        int jcol = rem >> 9, k = rem & 511;
        int kk = k >> 5, kg = (k >> 3) & 3, j = k & 7;
        int dst = NW + kk * 512 + (kg * 16 + jcol) * 8 + j;
        wt[dst] = f2bf(W6[k * 16 + jcol]);
    }
}

__global__ void mask_kernel(const float* __restrict__ x, float* __restrict__ mout, int B) {
    int i = blockIdx.x * 256 + threadIdx.x;
    if (i >= B) return;
    constexpr float bmin[4] = {0.0f, (float)(-PI_D), (float)(0.5 * PI_D), (float)(-0.85 * PI_D)};
    constexpr float bmax[4] = {(float)(PI_D), (float)(PI_D), (float)(0.85 * PI_D), (float)(-0.5 * PI_D)};
    float4 v = ((const float4*)x)[i];
    bool ok = (v.x >= bmin[0]) && (v.x <= bmax[0]) &&
              (v.y >= bmin[1]) && (v.y <= bmax[1]) &&
              (v.z >= bmin[2]) && (v.z <= bmax[2]) &&
              (v.w >= bmin[3]) && (v.w <= bmax[3]);
    mout[i] = ok ? 1.0f : 0.0f;
}

// One block = 64 points, ONE level (kernel arg). 8 waves, 75KB LDS, 2 blocks/CU.
// two_phase=1: write softmax weights (bf16) to wq and exit — zero table traffic,
// so the 2MB weight set stays L2-resident. two_phase=0: inline gather fallback.
__global__ __launch_bounds__(512, 4)
void fused_mlp(const float* __restrict__ x, const float* __restrict__ tables,
               const float* __restrict__ W1, const float* __restrict__ b1,
               const u16* __restrict__ wt,
               const float* __restrict__ b2, const float* __restrict__ b3,
               const float* __restrict__ b4, const float* __restrict__ b5,
               const float* __restrict__ b6, u16* __restrict__ wq,
               float* __restrict__ out, int level, int two_phase) {
    __shared__ u16 act[64 * 512];          // 64KB activations (XOR-swizzled rows)
    __shared__ float xsh[64 * 4];
    __shared__ float zsh[64 * 17];         // logits
    __shared__ float wsh[64 * 17];         // softmax weights (fallback only)

    const int tid = threadIdx.x;
    const int lane = tid & 63;
    const int wv = tid >> 6;               // wave 0..7
    const int ptile = blockIdx.x;
    const float res = g_res[level];

    if (tid < 256) xsh[tid] = x[ptile * 256 + tid];
    __syncthreads();

    // ---- layer 1: feat=[res,x] (K=5) -> 512, VALU. thread t owns column n=t.
    {
        const int n = tid;
        float w0 = W1[n], w1 = W1[512 + n], w2 = W1[1024 + n],
              w3 = W1[1536 + n], w4 = W1[2048 + n];
        float base = fmaf(res, w0, b1[n]);
        const int u0 = n >> 3, nlo = n & 7;
        for (int p = 0; p < 64; ++p) {
            float v = base;
            v = fmaf(xsh[p * 4 + 0], w1, v);
            v = fmaf(xsh[p * 4 + 1], w2, v);
            v = fmaf(xsh[p * 4 + 2], w3, v);
            v = fmaf(xsh[p * 4 + 3], w4, v);
            v = fmaxf(v, 0.0f);
            act[p * 512 + ((u0 ^ (p & 7)) << 3) + nlo] = f2bf(v);
        }
    }
    __syncthreads();

    // ---- layers 2..5: 512x512 bf16 MFMA. wave = 64 rows x 64 cols.
    const int row = lane & 15;
    const int kg = lane >> 4;
    for (int ly = 0; ly < 4; ++ly) {
        const u16* wbase = wt + ly * 262144;
        const float* bias = (ly == 0) ? b2 : (ly == 1) ? b3 : (ly == 2) ? b4 : b5;
        const int colbase = wv * 64;
        f32x4 acc[4][4];
#pragma unroll
        for (int rt = 0; rt < 4; ++rt)
#pragma unroll
            for (int ct = 0; ct < 4; ++ct) acc[rt][ct] = (f32x4){0.f, 0.f, 0.f, 0.f};

#pragma unroll 4
        for (int kk = 0; kk < 16; ++kk) {
            const int k0 = kk * 32 + kg * 8;
            short8 a[4], b[4];
#pragma unroll
            for (int rt = 0; rt < 4; ++rt) {
                int r = rt * 16 + row;
                int u = (k0 >> 3) ^ (r & 7);
                a[rt] = *(const short8*)&act[r * 512 + (u << 3)];
            }
#pragma unroll
            for (int ct = 0; ct < 4; ++ct)   // ONE contiguous 1KB wave load
                b[ct] = *(const short8*)&wbase[(wv * 4 + ct) * 8192 + kk * 512 + lane * 8];
#pragma unroll
            for (int rt = 0; rt < 4; ++rt)
#pragma unroll
                for (int ct = 0; ct < 4; ++ct)
                    acc[rt][ct] = __builtin_amdgcn_mfma_f32_16x16x32_bf16(a[rt], b[ct], acc[rt][ct], 0, 0, 0);
        }
        __syncthreads();   // all waves done reading act
        // epilogue: bias + relu -> act (bf16, swizzled). C/D: col=lane&15, row=kg*4+reg.
#pragma unroll
        for (int ct = 0; ct < 4; ++ct) {
            int col = colbase + ct * 16 + row;
            float bv = bias[col];
            int ucol = col >> 3, clo = col & 7;
#pragma unroll
            for (int rt = 0; rt < 4; ++rt)
#pragma unroll
                for (int q = 0; q < 4; ++q) {
                    int rg = rt * 16 + kg * 4 + q;
                    float v = fmaxf(acc[rt][ct][q] + bv, 0.0f);
                    act[rg * 512 + ((ucol ^ (rg & 7)) << 3) + clo] = f2bf(v);
                }
        }
        __syncthreads();
    }

    // ---- layer 6: 512 -> 16 logits via MFMA on waves 0..3
    if (wv < 4) {
        const u16* w6 = wt + 4 * 262144;
        f32x4 acc = {0.f, 0.f, 0.f, 0.f};
        const int r = wv * 16 + row;
#pragma unroll 4
        for (int kk = 0; kk < 16; ++kk) {
            int k0 = kk * 32 + kg * 8;
            int u = (k0 >> 3) ^ (r & 7);
            short8 a = *(const short8*)&act[r * 512 + (u << 3)];
            short8 b = *(const short8*)&w6[kk * 512 + lane * 8];
            acc = __builtin_amdgcn_mfma_f32_16x16x32_bf16(a, b, acc, 0, 0, 0);
        }
        float bv = b6[row];
#pragma unroll
        for (int q = 0; q < 4; ++q) {
            int rg = wv * 16 + kg * 4 + q;
            zsh[rg * 17 + row] = acc[q] + bv;
        }
    }
    __syncthreads();

    // ---- softmax over 16 (threads 0..63, one point each)
    if (tid < 64) {
        float zv[16];
        float m = -1e30f;
#pragma unroll
        for (int j = 0; j < 16; ++j) { zv[j] = zsh[tid * 17 + j]; m = fmaxf(m, zv[j]); }
        float s = 0.f;
#pragma unroll
        for (int j = 0; j < 16; ++j) { zv[j] = expf(zv[j] - m); s += zv[j]; }
        float inv = 1.0f / s;
        if (two_phase) {
            u16* wp = wq + (size_t)(ptile * 64 + tid) * 16;
#pragma unroll
            for (int j = 0; j < 16; ++j) wp[j] = f2bf(zv[j] * inv);
        } else {
#pragma unroll
            for (int j = 0; j < 16; ++j) wsh[tid * 17 + j] = zv[j] * inv;
        }
    }

    if (two_phase) return;
    __syncthreads();

    // ---- fallback inline gather: 8 threads/point, 2 corners each.
    {
        constexpr float bmin[4] = {0.0f, (float)(-PI_D), (float)(0.5 * PI_D), (float)(-0.85 * PI_D)};
        constexpr float bmax[4] = {(float)(PI_D), (float)(PI_D), (float)(0.85 * PI_D), (float)(-0.5 * PI_D)};
        constexpr uint32 primes[4] = {1u, 2654435761u, 805459861u, 3674653429u};
        const int p = tid >> 3;
        const int pr = tid & 7;
        uint32 ca[4], cb[4];
#pragma unroll
        for (int d = 0; d < 4; ++d) {
            float xv = xsh[p * 4 + d];
            float xc = fminf(fmaxf(xv, bmin[d]), bmax[d]);
            float g = (bmax[d] - bmin[d]) / res;
            float t = (xc - bmin[d]) / g;
            int bl = (int)floorf(t);
            ca[d] = (uint32)bl * primes[d];
            cb[d] = (uint32)(bl + 1) * primes[d];
        }
        float s0 = 0.f, s1 = 0.f;
        const float* tb = tables + (size_t)level * TABLE_SZ * 2;
#pragma unroll
        for (int vv = 0; vv < 2; ++vv) {
            int v = pr * 2 + vv;
            uint32 h = ((v & 8) ? cb[0] : ca[0]) ^ ((v & 4) ? cb[1] : ca[1]) ^
                       ((v & 2) ? cb[2] : ca[2]) ^ ((v & 1) ? cb[3] : ca[3]);
            float2 e = *(const float2*)(tb + (size_t)(h & HMASK) * 2);
            float wgt = wsh[p * 17 + v];
            s0 = fmaf(wgt, e.x, s0);
            s1 = fmaf(wgt, e.y, s1);
        }
#pragma unroll
        for (int sft = 1; sft < 8; sft <<= 1) {
            s0 += __shfl_xor(s0, sft, 64);
            s1 += __shfl_xor(s1, sft, 64);
        }
        if (pr == 0) {
            float* o = out + (size_t)(ptile * 64 + p) * 32 + level * 2;
            o[0] = s0;
            o[1] = s1;
        }
    }
}

// Phase B: pure gather for one level. Table (4MB) is L2-resident per XCD with
// nothing competing.
__global__ __launch_bounds__(256, 8)
void gather_kernel(const float* __restrict__ x, const float* __restrict__ tables,
                   const u16* __restrict__ wq, float* __restrict__ out, int level) {
    const int p = blockIdx.x * 256 + threadIdx.x;
    const float res = g_res[level];
    constexpr float bmin[4] = {0.0f, (float)(-PI_D), (float)(0.5 * PI_D), (float)(-0.85 * PI_D)};
    constexpr float bmax[4] = {(float)(PI_D), (float)(PI_D), (float)(0.85 * PI_D), (float)(-0.5 * PI_D)};
    constexpr uint32 primes[4] = {1u, 2654435761u, 805459861u, 3674653429u};

    float4 xv4 = ((const float4*)x)[p];
    float xd[4] = {xv4.x, xv4.y, xv4.z, xv4.w};
    uint32 ca[4], cb[4];
#pragma unroll
    for (int d = 0; d < 4; ++d) {
        float xc = fminf(fmaxf(xd[d], bmin[d]), bmax[d]);
        float g = (bmax[d] - bmin[d]) / res;
        float t = (xc - bmin[d]) / g;
        int bl = (int)floorf(t);
        ca[d] = (uint32)bl * primes[d];
        cb[d] = (uint32)(bl + 1) * primes[d];
    }
    const uint4* wp = (const uint4*)(wq + (size_t)p * 16);
    uint4 wa = wp[0], wb = wp[1];
    uint32 wu[8] = {wa.x, wa.y, wa.z, wa.w, wb.x, wb.y, wb.z, wb.w};

    const float* tb = tables + (size_t)level * TABLE_SZ * 2;
    float s0 = 0.f, s1 = 0.f;
#pragma unroll
    for (int v = 0; v < 16; ++v) {
        uint32 h = ((v & 8) ? cb[0] : ca[0]) ^ ((v & 4) ? cb[1] : ca[1]) ^
                   ((v & 2) ? cb[2] : ca[2]) ^ ((v & 1) ? cb[3] : ca[3]);
        float2 e = *(const float2*)(tb + (size_t)(h & HMASK) * 2);
        float wgt = bf2f((v & 1) ? (wu[v >> 1] >> 16) : (wu[v >> 1] & 0xFFFFu));
        s0 = fmaf(wgt, e.x, s0);
        s1 = fmaf(wgt, e.y, s1);
    }
    float* o = out + (size_t)p * 32 + level * 2;
    __builtin_nontemporal_store(s0, o);
    __builtin_nontemporal_store(s1, o + 1);
}

extern "C" void kernel_launch(void* const* d_in, const int* in_sizes, int n_in,
                              void* d_out, int out_size, void* d_ws, size_t ws_size,
                              hipStream_t stream) {
    const float* x      = (const float*)d_in[0];
    const float* tables = (const float*)d_in[1];
    const float* W1 = (const float*)d_in[2];
    const float* b1 = (const float*)d_in[3];
    const float* W2 = (const float*)d_in[4];
    const float* b2 = (const float*)d_in[5];
    const float* W3 = (const float*)d_in[6];
    const float* b3 = (const float*)d_in[7];
    const float* W4 = (const float*)d_in[8];
    const float* b4 = (const float*)d_in[9];
    const float* W5 = (const float*)d_in[10];
    const float* b5 = (const float*)d_in[11];
    const float* W6 = (const float*)d_in[12];
    const float* b6 = (const float*)d_in[13];

    const int B = in_sizes[0] / 4;          // 131072
    u16* wt = (u16*)d_ws;                   // 2.02 MB bf16 weights (tiled)
    u16* wq = (u16*)((char*)d_ws + (4 << 20));  // 4 MB per-level softmax weights
    const size_t need = (size_t)(4 << 20) + (size_t)NPTS * 16 * 2;  // 8.4 MB
    const int two_phase = (ws_size >= need) ? 1 : 0;

    const int prep_elems = 4 * 512 * 512 + 16 * 512;
    prep_weights<<<(prep_elems + 255) / 256, 256, 0, stream>>>(W2, W3, W4, W5, W6, wt);

    for (int level = 0; level < 16; ++level) {
        fused_mlp<<<dim3(B / 64), 512, 0, stream>>>(x, tables, W1, b1, wt,
                                                    b2, b3, b4, b5, b6,
                                                    wq, (float*)d_out, level, two_phase);
        if (two_phase)
            gather_kernel<<<dim3(B / 256), 256, 0, stream>>>(x, tables, wq,
                                                             (float*)d_out, level);
    }
    mask_kernel<<<(B + 255) / 256, 256, 0, stream>>>(x, (float*)d_out + (size_t)B * 32, B);
}